// Round 5
// baseline (274.828 us; speedup 1.0000x reference)
//
#include <hip/hip_runtime.h>

#define B 8
#define N 2048
#define FIN 10
#define D 128
#define ALPHA 0.02f
#define LOG2E 1.44269504088896340736f
#define BR 32     // rows per block, k_proj
#define NBLK_ATTN 256

typedef short bf8 __attribute__((ext_vector_type(8)));   // 8 bf16 in 4 VGPRs
typedef short s4v __attribute__((ext_vector_type(4)));
typedef float f32x4 __attribute__((ext_vector_type(4)));
typedef unsigned u4v __attribute__((ext_vector_type(4)));

__device__ __forceinline__ float lrelu(float x) { return x >= 0.f ? x : ALPHA * x; }

// f32 -> bf16 RNE (weights/Wh only)
__device__ __forceinline__ short f2b(float f) {
    unsigned u = __float_as_uint(f);
    return (short)((u + 0x7fffu + ((u >> 16) & 1u)) >> 16);
}

__device__ __forceinline__ float fexp2(float x) {
#if __has_builtin(__builtin_amdgcn_exp2f)
    return __builtin_amdgcn_exp2f(x);
#else
    return exp2f(x);
#endif
}

// pack two f32 -> two bf16 (truncation) in one v_perm
__device__ __forceinline__ unsigned pack2(float lo, float hi) {
#if __has_builtin(__builtin_amdgcn_perm)
    return __builtin_amdgcn_perm(__float_as_uint(hi), __float_as_uint(lo), 0x07060302u);
#else
    return (__float_as_uint(hi) & 0xFFFF0000u) | (__float_as_uint(lo) >> 16);
#endif
}

__device__ __forceinline__ unsigned enc_key(float v) {
    unsigned b = __float_as_uint(v);
    return (b & 0x80000000u) ? ~b : (b | 0x80000000u);
}
__device__ __forceinline__ float dec_key(unsigned k) {
    unsigned b = (k & 0x80000000u) ? (k & 0x7fffffffu) : ~k;
    return __uint_as_float(b);
}

// ---------------------------------------------------------------------------
// k_prep: one-time Wg fp32->bf16 (RNE) + zero-init pooled/cnt.
// ---------------------------------------------------------------------------
__global__ __launch_bounds__(256) void k_prep(
    const float* __restrict__ Wg, unsigned short* __restrict__ Wgb,
    unsigned* __restrict__ pooled, unsigned* __restrict__ cnt)
{
    const int g = blockIdx.x * 256 + threadIdx.x;    // 0..4095
    float4 f = *(const float4*)&Wg[g * 4];
    s4v v;
    v[0] = f2b(f.x); v[1] = f2b(f.y); v[2] = f2b(f.z); v[3] = f2b(f.w);
    *(s4v*)&Wgb[g * 4] = v;
    if (g < B * D) pooled[g] = 0u;
    if (g == B * D) *cnt = 0u;
}

// ---------------------------------------------------------------------------
// k_proj: x = lrelu(LN(h@W1^T+b1)) [bf16] ; Wh = x@Wg^T+bg via MFMA (fp32 acc);
// emits WhT bf16 [d][j] + e1,e2 (exp2-domain) fp32.
// Block = 32 rows, 256 threads (4 waves). Grid = 512.
// ---------------------------------------------------------------------------
__global__ __launch_bounds__(256) void k_proj(
    const float* __restrict__ h, const float* __restrict__ W1, const float* __restrict__ b1,
    const unsigned short* __restrict__ Wgb, const float* __restrict__ bg,
    const float* __restrict__ a1, const float* __restrict__ a2,
    unsigned short* __restrict__ WhT, float* __restrict__ e1g, float* __restrict__ e2g)
{
    __shared__ __align__(16) short xep_lds[32 * 136];
    __shared__ __align__(16) short wg_lds[D * 136];
    __shared__ float W1_lds[D * 11];
    __shared__ float h_lds[BR * FIN];
    __shared__ float ep1[2][BR], ep2[2][BR];

    const int t = threadIdx.x;
    const int r0 = blockIdx.x * BR;
    const int bb = r0 >> 11;
    const int jloc = r0 & (N - 1);

    for (int idx = t; idx < D * FIN; idx += 256)
        W1_lds[(idx / FIN) * 11 + (idx % FIN)] = W1[idx];
    for (int idx = t; idx < BR * FIN; idx += 256)
        h_lds[idx] = h[(size_t)r0 * FIN + idx];
    __syncthreads();

    // stage pre-converted Wg bf16 -> LDS (straight copy)
    {
        const int dr = t >> 4;
        const int j8 = t & 15;
        #pragma unroll
        for (int pass = 0; pass < 8; pass++) {
            int dd = pass * 16 + dr;
            *(bf8*)&wg_lds[dd * 136 + j8 * 8] = *(const bf8*)&Wgb[dd * D + j8 * 8];
        }
    }

    // phase 1: fc1 + LN + lrelu — all 8 rows hoisted for ILP
    const int w = t >> 6, lane = t & 63;
    {
        float b1v0 = b1[lane], b1v1 = b1[lane + 64];
        float sA[8], sB[8], smv[8], sqv[8];
        #pragma unroll
        for (int i = 0; i < 8; i++) {
            const float* hr = &h_lds[(w * 8 + i) * FIN];
            float s0 = b1v0, s1 = b1v1;
            #pragma unroll
            for (int k = 0; k < FIN; k++) {
                float hv = hr[k];
                s0 += hv * W1_lds[lane * 11 + k];
                s1 += hv * W1_lds[(lane + 64) * 11 + k];
            }
            sA[i] = s0; sB[i] = s1;
            smv[i] = s0 + s1; sqv[i] = s0 * s0 + s1 * s1;
        }
        #pragma unroll
        for (int m = 1; m <= 32; m <<= 1) {
            #pragma unroll
            for (int i = 0; i < 8; i++) { smv[i] += __shfl_xor(smv[i], m); sqv[i] += __shfl_xor(sqv[i], m); }
        }
        #pragma unroll
        for (int i = 0; i < 8; i++) {
            int r = w * 8 + i;
            float mean = smv[i] * (1.f / D);
            float var  = sqv[i] * (1.f / D) - mean * mean;
            float rs = rsqrtf(var + 1e-5f);
            xep_lds[r * 136 + lane]      = f2b(lrelu((sA[i] - mean) * rs));
            xep_lds[r * 136 + lane + 64] = f2b(lrelu((sB[i] - mean) * rs));
        }
    }
    __syncthreads();

    // phase 2: MFMA  Wh[32][128] = x @ Wg^T
    const int l15 = lane & 15, q = lane >> 4;
    const int mw = w & 1, np = w >> 1;
    f32x4 acc[4];
    #pragma unroll
    for (int nt = 0; nt < 4; nt++)
        #pragma unroll
        for (int r = 0; r < 4; r++) acc[nt][r] = 0.f;

    #pragma unroll
    for (int ks = 0; ks < 4; ks++) {
        bf8 av = *(const bf8*)&xep_lds[(mw * 16 + l15) * 136 + ks * 32 + q * 8];
        #pragma unroll
        for (int nt = 0; nt < 4; nt++) {
            bf8 bv = *(const bf8*)&wg_lds[((np * 4 + nt) * 16 + l15) * 136 + ks * 32 + q * 8];
            acc[nt] = __builtin_amdgcn_mfma_f32_16x16x32_bf16(av, bv, acc[nt], 0, 0, 0);
        }
    }

    // epilogue: +bg, e1/e2 partials
    float e1p[4] = {0.f, 0.f, 0.f, 0.f}, e2p[4] = {0.f, 0.f, 0.f, 0.f};
    #pragma unroll
    for (int nt = 0; nt < 4; nt++) {
        int col = (np * 4 + nt) * 16 + l15;
        float bgv = bg[col], a1v = a1[col], a2v = a2[col];
        #pragma unroll
        for (int r = 0; r < 4; r++) {
            float v = acc[nt][r] + bgv;
            acc[nt][r] = v;
            e1p[r] += v * a1v;
            e2p[r] += v * a2v;
        }
    }
    #pragma unroll
    for (int m = 1; m <= 8; m <<= 1) {
        #pragma unroll
        for (int r = 0; r < 4; r++) { e1p[r] += __shfl_xor(e1p[r], m); e2p[r] += __shfl_xor(e2p[r], m); }
    }
    if (l15 == 0) {
        #pragma unroll
        for (int r = 0; r < 4; r++) {
            ep1[np][mw * 16 + q * 4 + r] = e1p[r];
            ep2[np][mw * 16 + q * 4 + r] = e2p[r];
        }
    }
    __syncthreads();
    if (t < BR) {
        e1g[r0 + t] = (ep1[0][t] + ep1[1][t]) * LOG2E;
        e2g[r0 + t] = (ep2[0][t] + ep2[1][t]) * LOG2E;
    }
    #pragma unroll
    for (int nt = 0; nt < 4; nt++) {
        int col = (np * 4 + nt) * 16 + l15;
        #pragma unroll
        for (int r = 0; r < 4; r++)
            xep_lds[col * 36 + mw * 16 + q * 4 + r] = f2b(acc[nt][r]);
    }
    __syncthreads();
    {
        const int col = t >> 1, jh = (t & 1) * 16;
        unsigned short* dst = WhT + ((size_t)(bb * D + col)) * N + jloc + jh;
        #pragma unroll
        for (int i2 = 0; i2 < 4; i2++)
            *(uint2*)(dst + i2 * 4) = *(const uint2*)&xep_lds[col * 36 + jh + i2 * 4];
    }
}

// ---------------------------------------------------------------------------
// k_attn v3: barrier-free K-loop. One wave = one (batch, 16-row tile),
// full D, full N. MFMA fragments built directly from global loads (no LDS).
// 2-stage register ping-pong; fine-grained vmcnt, no vmcnt(0) drains.
// Grid = 256 blocks x 256 threads (4 waves = 4 tiles).
// ---------------------------------------------------------------------------
struct Stage {
    int4 a0, a1;          // adj[i0+l15][c*32 + q*8 + 0..7]
    float4 e20, e21;      // e2[c*32 + q*8 + 0..7]
    bf8 wv[8];            // WhT[nt*16+l15][c*32 + q*8 + 0..7]
};

__device__ __forceinline__ void load_stage(Stage& s, const int* adjp,
        const float* e2p, const unsigned short* whp, int c) {
    const int off = c * 32;
    s.a0  = *(const int4*)(adjp + off);
    s.a1  = *(const int4*)(adjp + off + 4);
    s.e20 = *(const float4*)(e2p + off);
    s.e21 = *(const float4*)(e2p + off + 4);
    #pragma unroll
    for (int nt = 0; nt < 8; nt++)
        s.wv[nt] = *(const bf8*)(whp + (size_t)nt * 16 * N + off);
}

__device__ __forceinline__ void consume(const Stage& s, float e1v,
        f32x4* acc, f32x4& accl, bf8 ones) {
    float t0 = e1v + s.e20.x, t1 = e1v + s.e20.y, t2 = e1v + s.e20.z, t3 = e1v + s.e20.w;
    float t4 = e1v + s.e21.x, t5 = e1v + s.e21.y, t6 = e1v + s.e21.z, t7 = e1v + s.e21.w;
    float p0 = s.a0.x ? fexp2(fmaxf(t0, ALPHA * t0)) : 0.f;
    float p1 = s.a0.y ? fexp2(fmaxf(t1, ALPHA * t1)) : 0.f;
    float p2 = s.a0.z ? fexp2(fmaxf(t2, ALPHA * t2)) : 0.f;
    float p3 = s.a0.w ? fexp2(fmaxf(t3, ALPHA * t3)) : 0.f;
    float p4 = s.a1.x ? fexp2(fmaxf(t4, ALPHA * t4)) : 0.f;
    float p5 = s.a1.y ? fexp2(fmaxf(t5, ALPHA * t5)) : 0.f;
    float p6 = s.a1.z ? fexp2(fmaxf(t6, ALPHA * t6)) : 0.f;
    float p7 = s.a1.w ? fexp2(fmaxf(t7, ALPHA * t7)) : 0.f;
    u4v uu;
    uu.x = pack2(p0, p1); uu.y = pack2(p2, p3);
    uu.z = pack2(p4, p5); uu.w = pack2(p6, p7);
    bf8 av = *(bf8*)&uu;
    #pragma unroll
    for (int nt = 0; nt < 8; nt++)
        acc[nt] = __builtin_amdgcn_mfma_f32_16x16x32_bf16(av, s.wv[nt], acc[nt], 0, 0, 0);
    accl = __builtin_amdgcn_mfma_f32_16x16x32_bf16(av, ones, accl, 0, 0, 0);
}

__global__ __launch_bounds__(256) void k_attn(
    const int* __restrict__ adj, const unsigned short* __restrict__ WhT,
    const float* __restrict__ e1g, const float* __restrict__ e2g,
    unsigned* __restrict__ pooled, unsigned* __restrict__ cnt,
    const float* __restrict__ W2, const float* __restrict__ b2,
    float* __restrict__ out)
{
    __shared__ unsigned maxb[4][D];
    __shared__ int finalflag;

    const int t = threadIdx.x;
    const int w = t >> 6, lane = t & 63;
    const int l15 = lane & 15, q = lane >> 4;
    const int bid = blockIdx.x;
    const int b = bid >> 5;                     // batch
    const int tile = (bid & 31) * 4 + w;        // 0..127
    const int i0 = tile * 16;

    const float e1v = e1g[b * N + i0 + l15];    // exp2-domain

    const int* adjp = adj + ((size_t)b * N + i0 + l15) * N + q * 8;
    const float* e2p = e2g + b * N + q * 8;
    const unsigned short* whp = WhT + (size_t)b * D * N + (size_t)l15 * N + q * 8;

    f32x4 acc[8], accl;
    #pragma unroll
    for (int nt = 0; nt < 8; nt++)
        #pragma unroll
        for (int r = 0; r < 4; r++) acc[nt][r] = 0.f;
    #pragma unroll
    for (int r = 0; r < 4; r++) accl[r] = 0.f;

    bf8 ones;
    #pragma unroll
    for (int i = 0; i < 8; i++) ones[i] = (short)0x3F80;

    Stage SA, SB;
    load_stage(SA, adjp, e2p, whp, 0);
    load_stage(SB, adjp, e2p, whp, 1);

    for (int c = 0; c < N / 32; c += 2) {
        consume(SA, e1v, acc, accl, ones);
        if (c + 2 < N / 32) load_stage(SA, adjp, e2p, whp, c + 2);
        consume(SB, e1v, acc, accl, ones);
        if (c + 3 < N / 32) load_stage(SB, adjp, e2p, whp, c + 3);
    }

    // in-wave epilogue: /l -> LN -> lrelu -> col max
    float smr[4], sqr[4];
    #pragma unroll
    for (int r = 0; r < 4; r++) {
        float rinv = 1.f / accl[r];
        float sm = 0.f, sq = 0.f;
        #pragma unroll
        for (int nt = 0; nt < 8; nt++) {
            float v = acc[nt][r] * rinv;
            acc[nt][r] = v;
            sm += v; sq += v * v;
        }
        smr[r] = sm; sqr[r] = sq;
    }
    #pragma unroll
    for (int m = 1; m <= 8; m <<= 1) {
        #pragma unroll
        for (int r = 0; r < 4; r++) { smr[r] += __shfl_xor(smr[r], m); sqr[r] += __shfl_xor(sqr[r], m); }
    }
    float mx[8];
    #pragma unroll
    for (int nt = 0; nt < 8; nt++) mx[nt] = -1e30f;
    #pragma unroll
    for (int r = 0; r < 4; r++) {
        float mean = smr[r] * (1.f / D);
        float var  = sqr[r] * (1.f / D) - mean * mean;
        float rs = rsqrtf(var + 1e-5f);
        #pragma unroll
        for (int nt = 0; nt < 8; nt++) {
            float v = lrelu((acc[nt][r] - mean) * rs);
            mx[nt] = fmaxf(mx[nt], v);
        }
    }
    #pragma unroll
    for (int m = 16; m <= 32; m <<= 1) {
        #pragma unroll
        for (int nt = 0; nt < 8; nt++) mx[nt] = fmaxf(mx[nt], __shfl_xor(mx[nt], m));
    }
    if (lane < 16) {
        #pragma unroll
        for (int nt = 0; nt < 8; nt++) maxb[w][nt * 16 + lane] = enc_key(mx[nt]);
    }
    __syncthreads();
    if (t < D) {
        unsigned m01 = maxb[0][t] > maxb[1][t] ? maxb[0][t] : maxb[1][t];
        unsigned m23 = maxb[2][t] > maxb[3][t] ? maxb[2][t] : maxb[3][t];
        atomicMax(&pooled[b * D + t], m01 > m23 ? m01 : m23);
    }
    __syncthreads();

    // completion counter; last block does final 128->2 matmul + log_softmax
    if (t == 0) {
        __threadfence();
        unsigned old = atomicAdd(cnt, 1u);
        finalflag = (old == NBLK_ATTN - 1) ? 1 : 0;
    }
    __syncthreads();
    if (finalflag) {
        const int fb = t >> 5;
        const int fq = t & 31;
        float s0 = 0.f, s1 = 0.f;
        #pragma unroll
        for (int m = 0; m < 4; m++) {
            int dd = fq + 32 * m;
            unsigned key = __hip_atomic_load(&pooled[fb * D + dd], __ATOMIC_RELAXED,
                                             __HIP_MEMORY_SCOPE_AGENT);
            float v = dec_key(key);
            s0 += v * W2[dd];
            s1 += v * W2[D + dd];
        }
        #pragma unroll
        for (int m = 1; m <= 16; m <<= 1) { s0 += __shfl_xor(s0, m); s1 += __shfl_xor(s1, m); }
        if (fq == 0) {
            float o0 = s0 + b2[0], o1 = s1 + b2[1];
            float mxv = fmaxf(o0, o1);
            float ls = logf(__expf(o0 - mxv) + __expf(o1 - mxv));
            out[fb * 2 + 0] = o0 - mxv - ls;
            out[fb * 2 + 1] = o1 - mxv - ls;
        }
    }
}

extern "C" void kernel_launch(void* const* d_in, const int* in_sizes, int n_in,
                              void* d_out, int out_size, void* d_ws, size_t ws_size,
                              hipStream_t stream) {
    const float* h   = (const float*)d_in[0];
    const int*   adj = (const int*)d_in[1];
    const float* W1  = (const float*)d_in[2];
    const float* b1  = (const float*)d_in[3];
    const float* Wg  = (const float*)d_in[4];
    const float* bg  = (const float*)d_in[5];
    const float* a1  = (const float*)d_in[6];
    const float* a2  = (const float*)d_in[7];
    const float* W2  = (const float*)d_in[8];
    const float* b2  = (const float*)d_in[9];
    float* out = (float*)d_out;

    unsigned short* WhT = (unsigned short*)d_ws;                       // B*D*N bf16
    float* e1g = (float*)((char*)d_ws + (size_t)B * D * N * 2);        // B*N f32
    float* e2g = e1g + (size_t)B * N;                                  // B*N f32
    unsigned* pooled = (unsigned*)(e2g + (size_t)B * N);               // B*D u32
    unsigned* cnt = pooled + (size_t)B * D;                            // 1 u32
    unsigned short* Wgb = (unsigned short*)(cnt + 4);                  // D*D bf16

    k_prep<<<16, 256, 0, stream>>>(Wg, Wgb, pooled, cnt);
    k_proj<<<(B * N) / BR, 256, 0, stream>>>(h, W1, b1, Wgb, bg, a1, a2,
                                             WhT, e1g, e2g);
    k_attn<<<NBLK_ATTN, 256, 0, stream>>>(adj, WhT, e1g, e2g, pooled, cnt,
                                          W2, b2, out);
}